// Round 2
// baseline (167.842 us; speedup 1.0000x reference)
//
#include <hip/hip_runtime.h>

#define N_NODES 10000
#define F_IN 256
#define HID 512
#define C_OUT 128
#define NEDGE 320000
#define BUCKET 128  // fixed per-node capacity; max degree ~60 for E=320K over N=10K

typedef __attribute__((ext_vector_type(8))) short short8;
typedef __attribute__((ext_vector_type(4))) float floatx4;

__device__ inline float bf2f_lo(unsigned u) { union { float f; unsigned i; } v; v.i = u << 16; return v.f; }
__device__ inline float bf2f_hi(unsigned u) { union { float f; unsigned i; } v; v.i = u & 0xFFFF0000u; return v.f; }
__device__ inline unsigned short f2bf(float f) {
    union { float f; unsigned i; } v; v.f = f;
    unsigned r = (v.i + 0x7FFFu + ((v.i >> 16) & 1u)) >> 16;
    return (unsigned short)r;
}
__device__ inline void add8(float* a, uint4 v) {
    a[0] += bf2f_lo(v.x); a[1] += bf2f_hi(v.x);
    a[2] += bf2f_lo(v.y); a[3] += bf2f_hi(v.y);
    a[4] += bf2f_lo(v.z); a[5] += bf2f_hi(v.z);
    a[6] += bf2f_lo(v.w); a[7] += bf2f_hi(v.w);
}
__device__ inline int sel4(int4 v, int g) {
    return g == 0 ? v.x : (g == 1 ? v.y : (g == 2 ? v.z : v.w));
}

// async global->LDS, 16B per lane; LDS dest = wave-uniform base + lane*16
__device__ __forceinline__ void gload_lds16(const unsigned short* g, unsigned short* l) {
    __builtin_amdgcn_global_load_lds((const __attribute__((address_space(1))) void*)g,
                                     (__attribute__((address_space(3))) void*)l, 16, 0, 0);
}

// ---------------- fused prep ----------------
__global__ __launch_bounds__(256)
void prep_kernel(const float4* __restrict__ xin, uint2* __restrict__ xb,
                 const float* __restrict__ W1l, const float* __restrict__ W1r,
                 const float* __restrict__ W2l, const float* __restrict__ W2r,
                 unsigned short* __restrict__ W1T, unsigned short* __restrict__ W2T,
                 int4* __restrict__ cursor4) {
    const int b = blockIdx.x;
    const int tid = threadIdx.x;
    if (b < 2500) {
        int i = b * 256 + tid;
        float4 v = xin[i];
        uint2 o;
        o.x = (unsigned)f2bf(v.x) | ((unsigned)f2bf(v.y) << 16);
        o.y = (unsigned)f2bf(v.z) | ((unsigned)f2bf(v.w) << 16);
        xb[i] = o;
        return;
    }
    if (b < 2884) {
        __shared__ float T[32][33];
        const int r = tid >> 3;          // 0..31
        const int c4 = (tid & 7) * 4;    // 0,4,..28
        if (b < 2756) {  // W1T: [512 n][512 k]
            int t = b - 2500;
            int kt = (t & 15) * 32, nt = (t >> 4) * 32;
            int kg = kt + r;
            const float* srcp = (kg < 256) ? (W1l + kg * 512) : (W1r + (kg - 256) * 512);
            float4 v = *(const float4*)(srcp + nt + c4);
            T[c4 + 0][r] = v.x; T[c4 + 1][r] = v.y; T[c4 + 2][r] = v.z; T[c4 + 3][r] = v.w;
            __syncthreads();
            ushort4 o;
            o.x = f2bf(T[r][c4 + 0]); o.y = f2bf(T[r][c4 + 1]);
            o.z = f2bf(T[r][c4 + 2]); o.w = f2bf(T[r][c4 + 3]);
            *(ushort4*)(W1T + (long long)(nt + r) * 512 + kt + c4) = o;
        } else {         // W2T: [256 n][512 k]
            int t = b - 2756;
            int kt = (t & 15) * 32, col0 = (t >> 4) * 32;
            const float* Wsrc; int coloff;
            if (col0 < 128) { Wsrc = W2l; coloff = col0; } else { Wsrc = W2r; coloff = col0 - 128; }
            float4 v = *(const float4*)(Wsrc + (long long)(kt + r) * 128 + coloff + c4);
            T[c4 + 0][r] = v.x; T[c4 + 1][r] = v.y; T[c4 + 2][r] = v.z; T[c4 + 3][r] = v.w;
            __syncthreads();
            ushort4 o;
            o.x = f2bf(T[r][c4 + 0]); o.y = f2bf(T[r][c4 + 1]);
            o.z = f2bf(T[r][c4 + 2]); o.w = f2bf(T[r][c4 + 3]);
            *(ushort4*)(W2T + (long long)(col0 + r) * 512 + kt + c4) = o;
        }
        return;
    }
    {
        int i = (b - 2884) * 256 + tid;
        if (i < (N_NODES + 3) / 4) cursor4[i] = make_int4(0, 0, 0, 0);
    }
}

// ---------------- bucket fill: one atomic pass ----------------
__global__ __launch_bounds__(256)
void fill_kernel(const int* __restrict__ src, const int* __restrict__ dst,
                 int* __restrict__ cursor, int* __restrict__ bucket, int E) {
    int e = blockIdx.x * 256 + threadIdx.x;
    if (e < E) {
        int d = dst[e];
        int pos = atomicAdd(&cursor[d], 1);
        bucket[(d << 7) + pos] = src[e];
    }
}

// ---------------- gather-aggregate, HALF feature slice (128 bf16 = 256B/row) ----------------
// One wave per node; 4-way edge split (4 loads in flight x unroll4 = 16 edges/iter).
// Working set per pass = 10000 x 256B = 2.56MB < 4MB/XCD L2 -> L2-resident gather.
// feat/outp are pre-offset by the half (column offset); row stride = 256 shorts.
__global__ __launch_bounds__(256)
void gather_agg_half(const unsigned short* __restrict__ feat,
                     const int* __restrict__ cursor,
                     const int* __restrict__ bucket,
                     unsigned short* __restrict__ outp, int nnodes) {
    const int wid = (blockIdx.x * 256 + threadIdx.x) >> 6;
    if (wid >= nnodes) return;
    const int lane = threadIdx.x & 63;
    const int g = lane >> 4;       // 0..3
    const int sub = lane & 15;
    const long long myoff = (long long)sub * 8;  // shorts (16B)
    const int cnt = __builtin_amdgcn_readfirstlane(cursor[wid]);
    const int* row = bucket + (wid << 7);

    float acc[8] = {0.f, 0.f, 0.f, 0.f, 0.f, 0.f, 0.f, 0.f};
    float accB[8] = {0.f, 0.f, 0.f, 0.f, 0.f, 0.f, 0.f, 0.f};

    int j = 0;
    for (; j + 16 <= cnt; j += 16) {
        const int4 ia = *(const int4*)(row + j);
        const int4 ib = *(const int4*)(row + j + 4);
        const int4 ic = *(const int4*)(row + j + 8);
        const int4 id = *(const int4*)(row + j + 12);
        int i0 = sel4(ia, g), i1 = sel4(ib, g), i2 = sel4(ic, g), i3 = sel4(id, g);
        uint4 v0 = *(const uint4*)(feat + (long long)i0 * 256 + myoff);
        uint4 v1 = *(const uint4*)(feat + (long long)i1 * 256 + myoff);
        uint4 v2 = *(const uint4*)(feat + (long long)i2 * 256 + myoff);
        uint4 v3 = *(const uint4*)(feat + (long long)i3 * 256 + myoff);
        add8(acc, v0); add8(accB, v1); add8(acc, v2); add8(accB, v3);
    }
    for (; j + 8 <= cnt; j += 8) {
        const int4 ia = *(const int4*)(row + j);
        const int4 ib = *(const int4*)(row + j + 4);
        int i0 = sel4(ia, g), i1 = sel4(ib, g);
        uint4 v0 = *(const uint4*)(feat + (long long)i0 * 256 + myoff);
        uint4 v1 = *(const uint4*)(feat + (long long)i1 * 256 + myoff);
        add8(acc, v0); add8(accB, v1);
    }
    for (; j + 4 <= cnt; j += 4) {
        const int4 ia = *(const int4*)(row + j);
        int i0 = sel4(ia, g);
        uint4 v = *(const uint4*)(feat + (long long)i0 * 256 + myoff);
        add8(acc, v);
    }
    int rem = cnt - j;  // 0..3
    if (rem > 0) {
        int idx = row[j + (g < rem ? g : 0)];
        uint4 v = *(const uint4*)(feat + (long long)idx * 256 + myoff);
        if (g < rem) add8(acc, v);
    }
#pragma unroll
    for (int k = 0; k < 8; ++k) acc[k] += accB[k];
#pragma unroll
    for (int k = 0; k < 8; ++k) acc[k] += __shfl_xor(acc[k], 16, 64);
#pragma unroll
    for (int k = 0; k < 8; ++k) acc[k] += __shfl_xor(acc[k], 32, 64);

    if (lane < 16) {
        uint4 o;
        o.x = (unsigned)f2bf(acc[0]) | ((unsigned)f2bf(acc[1]) << 16);
        o.y = (unsigned)f2bf(acc[2]) | ((unsigned)f2bf(acc[3]) << 16);
        o.z = (unsigned)f2bf(acc[4]) | ((unsigned)f2bf(acc[5]) << 16);
        o.w = (unsigned)f2bf(acc[6]) | ((unsigned)f2bf(acc[7]) << 16);
        *(uint4*)(outp + (long long)wid * 256 + myoff) = o;
    }
}

// ---------------- gather-accumulate (bf16, F=128 -> fp32 out), unroll-16: 4 loads in flight ----------------
__global__ __launch_bounds__(256)
void gather_acc_128(const unsigned short* __restrict__ feat,
                    const int* __restrict__ cursor,
                    const int* __restrict__ bucket,
                    float* __restrict__ outp, int nnodes) {
    const int wid = (blockIdx.x * 256 + threadIdx.x) >> 6;
    if (wid >= nnodes) return;
    const int lane = threadIdx.x & 63;
    const int g = lane >> 4;       // 0..3
    const int sub = lane & 15;
    const long long myoff = (long long)sub * 8;  // shorts (16B)
    const int cnt = __builtin_amdgcn_readfirstlane(cursor[wid]);
    const int* row = bucket + (wid << 7);

    float4 c0 = make_float4(0.f, 0.f, 0.f, 0.f), c1 = c0;
    float* orow = outp + (long long)wid * 128 + sub * 8;
    if (lane < 16) {
        c0 = *(const float4*)(orow);
        c1 = *(const float4*)(orow + 4);
    }

    float acc[8] = {0.f, 0.f, 0.f, 0.f, 0.f, 0.f, 0.f, 0.f};
    float accB[8] = {0.f, 0.f, 0.f, 0.f, 0.f, 0.f, 0.f, 0.f};

    int j = 0;
    for (; j + 16 <= cnt; j += 16) {
        const int4 ia = *(const int4*)(row + j);
        const int4 ib = *(const int4*)(row + j + 4);
        const int4 ic = *(const int4*)(row + j + 8);
        const int4 id = *(const int4*)(row + j + 12);
        int i0 = sel4(ia, g), i1 = sel4(ib, g), i2 = sel4(ic, g), i3 = sel4(id, g);
        uint4 v0 = *(const uint4*)(feat + (long long)i0 * 128 + myoff);
        uint4 v1 = *(const uint4*)(feat + (long long)i1 * 128 + myoff);
        uint4 v2 = *(const uint4*)(feat + (long long)i2 * 128 + myoff);
        uint4 v3 = *(const uint4*)(feat + (long long)i3 * 128 + myoff);
        add8(acc, v0); add8(accB, v1); add8(acc, v2); add8(accB, v3);
    }
    for (; j + 8 <= cnt; j += 8) {
        const int4 ia = *(const int4*)(row + j);
        const int4 ib = *(const int4*)(row + j + 4);
        int i0 = sel4(ia, g), i1 = sel4(ib, g);
        uint4 v0 = *(const uint4*)(feat + (long long)i0 * 128 + myoff);
        uint4 v1 = *(const uint4*)(feat + (long long)i1 * 128 + myoff);
        add8(acc, v0); add8(accB, v1);
    }
    for (; j + 4 <= cnt; j += 4) {
        const int4 ia = *(const int4*)(row + j);
        int i0 = sel4(ia, g);
        uint4 v = *(const uint4*)(feat + (long long)i0 * 128 + myoff);
        add8(acc, v);
    }
    int rem = cnt - j;  // 0..3
    if (rem > 0) {
        int idx = row[j + (g < rem ? g : 0)];
        uint4 v = *(const uint4*)(feat + (long long)idx * 128 + myoff);
        if (g < rem) add8(acc, v);
    }
#pragma unroll
    for (int k = 0; k < 8; ++k) acc[k] += accB[k];
#pragma unroll
    for (int k = 0; k < 8; ++k) acc[k] += __shfl_xor(acc[k], 16, 64);
#pragma unroll
    for (int k = 0; k < 8; ++k) acc[k] += __shfl_xor(acc[k], 32, 64);

    if (lane < 16) {
        c0.x += acc[0]; c0.y += acc[1]; c0.z += acc[2]; c0.w += acc[3];
        c1.x += acc[4]; c1.y += acc[5]; c1.z += acc[6]; c1.w += acc[7];
        *(float4*)(orow) = c0;
        *(float4*)(orow + 4) = c1;
    }
}

// ---------------- MFMA dual-segment GEMM: BM=128, BN=64, BK=64 ----------------
// Staging via global_load_lds width-16, linear LDS rows, XOR chunk swizzle (see R1).
// MODE 0: C0 = relu(acc + bias) -> h bf16 [M][Nfull]
// MODE 1: cols<128 -> C0 = p bf16 [M][128]; cols>=128 -> C1 = out fp32 [M][128] + bias
template <int MODE>
__global__ __launch_bounds__(256)
void mfma_gemm(const unsigned short* __restrict__ A1, int K1,
               const unsigned short* __restrict__ A2, int K2,
               const unsigned short* __restrict__ BT,
               const float* __restrict__ bias,
               void* __restrict__ C0v, void* __restrict__ C1v,
               int M, int Nfull) {
    __shared__ unsigned short A_lds[128][64];
    __shared__ unsigned short B_lds[64][64];

    const int t = threadIdx.x;
    const int lane = t & 63;
    const int w = t >> 6;       // wave row-group 0..3
    const int l15 = lane & 15;
    const int quad = lane >> 4;
    const int row0 = blockIdx.x * 128;
    const int col0 = blockIdx.y * 64;
    const int Ktot = K1 + K2;

    floatx4 acc[2][4];
#pragma unroll
    for (int i = 0; i < 2; ++i)
#pragma unroll
        for (int cf = 0; cf < 4; ++cf) acc[i][cf] = (floatx4){0.f, 0.f, 0.f, 0.f};

    const int lr = lane >> 3;            // 0..7
    const int gchunk = (lane & 7) ^ lr;  // involution partner of (l&7) for row%8 == lr

    for (int k0 = 0; k0 < Ktot; k0 += 64) {
        const unsigned short* Ap;
        int astride, acol;
        if (k0 < K1) { Ap = A1; astride = K1; acol = k0; }
        else         { Ap = A2; astride = K2; acol = k0 - K1; }
#pragma unroll
        for (int it = 0; it < 4; ++it) {
            int r = w * 32 + it * 8 + lr;
            int gr = row0 + r; if (gr >= M) gr = M - 1;
            gload_lds16(Ap + (long long)gr * astride + acol + gchunk * 8,
                        &A_lds[w * 32 + it * 8][0]);
        }
#pragma unroll
        for (int it = 0; it < 2; ++it) {
            int r = w * 16 + it * 8 + lr;
            gload_lds16(BT + (long long)(col0 + r) * Ktot + k0 + gchunk * 8,
                        &B_lds[w * 16 + it * 8][0]);
        }
        __syncthreads();
#pragma unroll
        for (int kc = 0; kc < 2; ++kc) {
            const int sa = ((kc * 4 + quad) ^ (l15 & 7)) * 8;  // swizzled short offset
            short8 a0 = *(short8*)&A_lds[w * 32 + l15][sa];
            short8 a1 = *(short8*)&A_lds[w * 32 + 16 + l15][sa];
            short8 bb[4];
#pragma unroll
            for (int cf = 0; cf < 4; ++cf)
                bb[cf] = *(short8*)&B_lds[cf * 16 + l15][sa];
#pragma unroll
            for (int cf = 0; cf < 4; ++cf) {
                acc[0][cf] = __builtin_amdgcn_mfma_f32_16x16x32_bf16(a0, bb[cf], acc[0][cf], 0, 0, 0);
                acc[1][cf] = __builtin_amdgcn_mfma_f32_16x16x32_bf16(a1, bb[cf], acc[1][cf], 0, 0, 0);
            }
        }
        __syncthreads();
    }

    // epilogue: row = row0 + w*32 + i*16 + quad*4 + reg; col = col0 + cf*16 + l15
    const int rbase = row0 + w * 32 + quad * 4;

    if (MODE == 0) {
        unsigned short* C0 = (unsigned short*)C0v;
#pragma unroll
        for (int cf = 0; cf < 4; ++cf) {
            const int cj = col0 + cf * 16 + l15;
            const float bi = bias[cj];
#pragma unroll
            for (int i = 0; i < 2; ++i) {
#pragma unroll
                for (int reg = 0; reg < 4; ++reg) {
                    int r = rbase + i * 16 + reg;
                    if (r >= M) continue;
                    C0[(long long)r * Nfull + cj] = f2bf(fmaxf(acc[i][cf][reg] + bi, 0.f));
                }
            }
        }
    } else {
        if (col0 < 128) {
            unsigned short* C0 = (unsigned short*)C0v;
#pragma unroll
            for (int cf = 0; cf < 4; ++cf) {
                const int cj = col0 + cf * 16 + l15;
#pragma unroll
                for (int i = 0; i < 2; ++i) {
#pragma unroll
                    for (int reg = 0; reg < 4; ++reg) {
                        int r = rbase + i * 16 + reg;
                        if (r >= M) continue;
                        C0[(long long)r * 128 + cj] = f2bf(acc[i][cf][reg]);
                    }
                }
            }
        } else {
            float* C1 = (float*)C1v;
#pragma unroll
            for (int cf = 0; cf < 4; ++cf) {
                const int d = col0 - 128 + cf * 16 + l15;
                const float bi = bias[d];
#pragma unroll
                for (int i = 0; i < 2; ++i) {
#pragma unroll
                    for (int reg = 0; reg < 4; ++reg) {
                        int r = rbase + i * 16 + reg;
                        if (r >= M) continue;
                        C1[(long long)r * 128 + d] = acc[i][cf][reg] + bi;
                    }
                }
            }
        }
    }
}

extern "C" void kernel_launch(void* const* d_in, const int* in_sizes, int n_in,
                              void* d_out, int out_size, void* d_ws, size_t ws_size,
                              hipStream_t stream) {
    const float* x   = (const float*)d_in[0];
    const int*   ei  = (const int*)d_in[1];
    const float* W1l = (const float*)d_in[2];
    const float* b1  = (const float*)d_in[3];
    const float* W1r = (const float*)d_in[4];
    const float* W2l = (const float*)d_in[5];
    const float* b2  = (const float*)d_in[6];
    const float* W2r = (const float*)d_in[7];
    float* out = (float*)d_out;

    const int E = in_sizes[1] / 2;
    const int* src = ei;
    const int* dst = ei + E;

    // ---- workspace layout (all 16B aligned) ----
    char* w = (char*)d_ws;
    int* cursor  = (int*)w;             w += 10016 * sizeof(int);
    int* bucket  = (int*)w;             w += (long long)N_NODES * BUCKET * sizeof(int);
    unsigned short* xb    = (unsigned short*)w; w += (long long)N_NODES * F_IN * 2;
    unsigned short* agg1b = (unsigned short*)w; w += (long long)N_NODES * F_IN * 2;
    unsigned short* W1T   = (unsigned short*)w; w += 512 * 512 * 2;
    unsigned short* W2T   = (unsigned short*)w; w += 256 * 512 * 2;
    unsigned short* h     = (unsigned short*)w; w += (long long)N_NODES * HID * 2;
    unsigned short* p     = (unsigned short*)w; w += (long long)N_NODES * C_OUT * 2;

    // ---- prep (convert/transpose/zero-cursor) + bucket fill ----
    prep_kernel<<<2894, 256, 0, stream>>>((const float4*)x, (uint2*)xb,
                                          W1l, W1r, W2l, W2r, W1T, W2T, (int4*)cursor);
    fill_kernel<<<(E + 255) / 256, 256, 0, stream>>>(src, dst, cursor, bucket, E);

    const int agg_blocks = (N_NODES * 64 + 255) / 256;

    // ---- layer 1: two half-feature gather passes (each pass L2-resident per XCD) ----
    gather_agg_half<<<agg_blocks, 256, 0, stream>>>(xb,       cursor, bucket, agg1b,       N_NODES);
    gather_agg_half<<<agg_blocks, 256, 0, stream>>>(xb + 128, cursor, bucket, agg1b + 128, N_NODES);
    {
        dim3 grid((N_NODES + 127) / 128, HID / 64);
        mfma_gemm<0><<<grid, 256, 0, stream>>>(agg1b, F_IN, xb, F_IN, W1T, b1,
                                               (void*)h, (void*)nullptr, N_NODES, HID);
    }

    // ---- layer 2 (aggregation swapped past the linear) ----
    {
        dim3 grid((N_NODES + 127) / 128, 256 / 64);
        mfma_gemm<1><<<grid, 256, 0, stream>>>(h, HID, h, 0, W2T, b2,
                                               (void*)p, (void*)out, N_NODES, 256);
    }
    gather_acc_128<<<agg_blocks, 256, 0, stream>>>(p, cursor, bucket, out, N_NODES);
}

// Round 3
// 160.926 us; speedup vs baseline: 1.0430x; 1.0430x over previous
//
#include <hip/hip_runtime.h>

#define N_NODES 10000
#define F_IN 256
#define HID 512
#define C_OUT 128
#define NEDGE 320000
#define BUCKET 128  // fixed per-node capacity; max degree ~60 for E=320K over N=10K

typedef __attribute__((ext_vector_type(8))) short short8;
typedef __attribute__((ext_vector_type(4))) float floatx4;

__device__ inline float bf2f_lo(unsigned u) { union { float f; unsigned i; } v; v.i = u << 16; return v.f; }
__device__ inline float bf2f_hi(unsigned u) { union { float f; unsigned i; } v; v.i = u & 0xFFFF0000u; return v.f; }
__device__ inline unsigned short f2bf(float f) {
    union { float f; unsigned i; } v; v.f = f;
    unsigned r = (v.i + 0x7FFFu + ((v.i >> 16) & 1u)) >> 16;
    return (unsigned short)r;
}
__device__ inline void add8(float* a, uint4 v) {
    a[0] += bf2f_lo(v.x); a[1] += bf2f_hi(v.x);
    a[2] += bf2f_lo(v.y); a[3] += bf2f_hi(v.y);
    a[4] += bf2f_lo(v.z); a[5] += bf2f_hi(v.z);
    a[6] += bf2f_lo(v.w); a[7] += bf2f_hi(v.w);
}
__device__ inline int sel4(int4 v, int g) {
    return g == 0 ? v.x : (g == 1 ? v.y : (g == 2 ? v.z : v.w));
}

// async global->LDS, 16B per lane; LDS dest = wave-uniform base + lane*16
__device__ __forceinline__ void gload_lds16(const unsigned short* g, unsigned short* l) {
    __builtin_amdgcn_global_load_lds((const __attribute__((address_space(1))) void*)g,
                                     (__attribute__((address_space(3))) void*)l, 16, 0, 0);
}

// ---------------- fused prep + edge-bucket fill ----------------
// cursor is zeroed by hipMemsetAsync before this kernel (stream-ordered).
// blocks [0,2500): x fp32->bf16 convert; [2500,2884): W transposes;
// [2884, 2884+ceil(E/256)): edge bucket fill (independent of the other sections).
__global__ __launch_bounds__(256)
void prep_fill_kernel(const float4* __restrict__ xin, uint2* __restrict__ xb,
                      const float* __restrict__ W1l, const float* __restrict__ W1r,
                      const float* __restrict__ W2l, const float* __restrict__ W2r,
                      unsigned short* __restrict__ W1T, unsigned short* __restrict__ W2T,
                      const int* __restrict__ src, const int* __restrict__ dst,
                      int* __restrict__ cursor, int* __restrict__ bucket, int E) {
    const int b = blockIdx.x;
    const int tid = threadIdx.x;
    if (b < 2500) {
        int i = b * 256 + tid;
        float4 v = xin[i];
        uint2 o;
        o.x = (unsigned)f2bf(v.x) | ((unsigned)f2bf(v.y) << 16);
        o.y = (unsigned)f2bf(v.z) | ((unsigned)f2bf(v.w) << 16);
        xb[i] = o;
        return;
    }
    if (b < 2884) {
        __shared__ float T[32][33];
        const int r = tid >> 3;          // 0..31
        const int c4 = (tid & 7) * 4;    // 0,4,..28
        if (b < 2756) {  // W1T: [512 n][512 k]
            int t = b - 2500;
            int kt = (t & 15) * 32, nt = (t >> 4) * 32;
            int kg = kt + r;
            const float* srcp = (kg < 256) ? (W1l + kg * 512) : (W1r + (kg - 256) * 512);
            float4 v = *(const float4*)(srcp + nt + c4);
            T[c4 + 0][r] = v.x; T[c4 + 1][r] = v.y; T[c4 + 2][r] = v.z; T[c4 + 3][r] = v.w;
            __syncthreads();
            ushort4 o;
            o.x = f2bf(T[r][c4 + 0]); o.y = f2bf(T[r][c4 + 1]);
            o.z = f2bf(T[r][c4 + 2]); o.w = f2bf(T[r][c4 + 3]);
            *(ushort4*)(W1T + (long long)(nt + r) * 512 + kt + c4) = o;
        } else {         // W2T: [256 n][512 k]
            int t = b - 2756;
            int kt = (t & 15) * 32, col0 = (t >> 4) * 32;
            const float* Wsrc; int coloff;
            if (col0 < 128) { Wsrc = W2l; coloff = col0; } else { Wsrc = W2r; coloff = col0 - 128; }
            float4 v = *(const float4*)(Wsrc + (long long)(kt + r) * 128 + coloff + c4);
            T[c4 + 0][r] = v.x; T[c4 + 1][r] = v.y; T[c4 + 2][r] = v.z; T[c4 + 3][r] = v.w;
            __syncthreads();
            ushort4 o;
            o.x = f2bf(T[r][c4 + 0]); o.y = f2bf(T[r][c4 + 1]);
            o.z = f2bf(T[r][c4 + 2]); o.w = f2bf(T[r][c4 + 3]);
            *(ushort4*)(W2T + (long long)(col0 + r) * 512 + kt + c4) = o;
        }
        return;
    }
    {
        int e = (b - 2884) * 256 + tid;
        if (e < E) {
            int d = dst[e];
            int pos = atomicAdd(&cursor[d], 1);
            bucket[(d << 7) + pos] = src[e];
        }
    }
}

// ---------------- gather-aggregate (bf16, F=256), unroll-16: 8 loads in flight ----------------
__global__ __launch_bounds__(256)
void gather_agg_256(const unsigned short* __restrict__ feat,
                    const int* __restrict__ cursor,
                    const int* __restrict__ bucket,
                    unsigned short* __restrict__ outp, int nnodes) {
    const int wid = (blockIdx.x * 256 + threadIdx.x) >> 6;
    if (wid >= nnodes) return;
    const int lane = threadIdx.x & 63;
    const int half = lane >> 5;
    const int sub = lane & 31;
    const long long myoff = (long long)sub * 8;  // shorts
    const int cnt = __builtin_amdgcn_readfirstlane(cursor[wid]);
    const int* row = bucket + (wid << 7);

    float acc[8] = {0.f, 0.f, 0.f, 0.f, 0.f, 0.f, 0.f, 0.f};
    float accB[8] = {0.f, 0.f, 0.f, 0.f, 0.f, 0.f, 0.f, 0.f};

    int j = 0;
    for (; j + 16 <= cnt; j += 16) {
        const int4 ia = *(const int4*)(row + j);
        const int4 ib = *(const int4*)(row + j + 4);
        const int4 ic = *(const int4*)(row + j + 8);
        const int4 id = *(const int4*)(row + j + 12);
        int i0 = half ? ia.y : ia.x;
        int i1 = half ? ia.w : ia.z;
        int i2 = half ? ib.y : ib.x;
        int i3 = half ? ib.w : ib.z;
        int i4 = half ? ic.y : ic.x;
        int i5 = half ? ic.w : ic.z;
        int i6 = half ? id.y : id.x;
        int i7 = half ? id.w : id.z;
        uint4 v0 = *(const uint4*)(feat + (long long)i0 * 256 + myoff);
        uint4 v1 = *(const uint4*)(feat + (long long)i1 * 256 + myoff);
        uint4 v2 = *(const uint4*)(feat + (long long)i2 * 256 + myoff);
        uint4 v3 = *(const uint4*)(feat + (long long)i3 * 256 + myoff);
        uint4 v4 = *(const uint4*)(feat + (long long)i4 * 256 + myoff);
        uint4 v5 = *(const uint4*)(feat + (long long)i5 * 256 + myoff);
        uint4 v6 = *(const uint4*)(feat + (long long)i6 * 256 + myoff);
        uint4 v7 = *(const uint4*)(feat + (long long)i7 * 256 + myoff);
        add8(acc, v0); add8(accB, v1); add8(acc, v2); add8(accB, v3);
        add8(acc, v4); add8(accB, v5); add8(acc, v6); add8(accB, v7);
    }
    for (; j + 8 <= cnt; j += 8) {
        const int4 ia = *(const int4*)(row + j);
        const int4 ib = *(const int4*)(row + j + 4);
        int i0 = half ? ia.y : ia.x;
        int i1 = half ? ia.w : ia.z;
        int i2 = half ? ib.y : ib.x;
        int i3 = half ? ib.w : ib.z;
        uint4 v0 = *(const uint4*)(feat + (long long)i0 * 256 + myoff);
        uint4 v1 = *(const uint4*)(feat + (long long)i1 * 256 + myoff);
        uint4 v2 = *(const uint4*)(feat + (long long)i2 * 256 + myoff);
        uint4 v3 = *(const uint4*)(feat + (long long)i3 * 256 + myoff);
        add8(acc, v0); add8(accB, v1); add8(acc, v2); add8(accB, v3);
    }
    for (; j + 2 <= cnt; j += 2) {
        const int2 e = *(const int2*)(row + j);
        int i0 = half ? e.y : e.x;
        uint4 v = *(const uint4*)(feat + (long long)i0 * 256 + myoff);
        add8(acc, v);
    }
    if (j < cnt) {
        int i0 = row[j];
        uint4 v = *(const uint4*)(feat + (long long)i0 * 256 + myoff);
        if (half == 0) add8(acc, v);
    }
#pragma unroll
    for (int k = 0; k < 8; ++k) acc[k] += accB[k];
#pragma unroll
    for (int k = 0; k < 8; ++k) acc[k] += __shfl_xor(acc[k], 32, 64);

    if (half == 0) {
        uint4 o;
        o.x = (unsigned)f2bf(acc[0]) | ((unsigned)f2bf(acc[1]) << 16);
        o.y = (unsigned)f2bf(acc[2]) | ((unsigned)f2bf(acc[3]) << 16);
        o.z = (unsigned)f2bf(acc[4]) | ((unsigned)f2bf(acc[5]) << 16);
        o.w = (unsigned)f2bf(acc[6]) | ((unsigned)f2bf(acc[7]) << 16);
        *(uint4*)(outp + (long long)wid * 256 + myoff) = o;
    }
}

// ---------------- gather-accumulate (bf16, F=128 -> fp32 out), unroll-16: 4 loads in flight ----------------
__global__ __launch_bounds__(256)
void gather_acc_128(const unsigned short* __restrict__ feat,
                    const int* __restrict__ cursor,
                    const int* __restrict__ bucket,
                    float* __restrict__ outp, int nnodes) {
    const int wid = (blockIdx.x * 256 + threadIdx.x) >> 6;
    if (wid >= nnodes) return;
    const int lane = threadIdx.x & 63;
    const int g = lane >> 4;       // 0..3
    const int sub = lane & 15;
    const long long myoff = (long long)sub * 8;  // shorts (16B)
    const int cnt = __builtin_amdgcn_readfirstlane(cursor[wid]);
    const int* row = bucket + (wid << 7);

    float4 c0 = make_float4(0.f, 0.f, 0.f, 0.f), c1 = c0;
    float* orow = outp + (long long)wid * 128 + sub * 8;
    if (lane < 16) {
        c0 = *(const float4*)(orow);
        c1 = *(const float4*)(orow + 4);
    }

    float acc[8] = {0.f, 0.f, 0.f, 0.f, 0.f, 0.f, 0.f, 0.f};
    float accB[8] = {0.f, 0.f, 0.f, 0.f, 0.f, 0.f, 0.f, 0.f};

    int j = 0;
    for (; j + 16 <= cnt; j += 16) {
        const int4 ia = *(const int4*)(row + j);
        const int4 ib = *(const int4*)(row + j + 4);
        const int4 ic = *(const int4*)(row + j + 8);
        const int4 id = *(const int4*)(row + j + 12);
        int i0 = sel4(ia, g), i1 = sel4(ib, g), i2 = sel4(ic, g), i3 = sel4(id, g);
        uint4 v0 = *(const uint4*)(feat + (long long)i0 * 128 + myoff);
        uint4 v1 = *(const uint4*)(feat + (long long)i1 * 128 + myoff);
        uint4 v2 = *(const uint4*)(feat + (long long)i2 * 128 + myoff);
        uint4 v3 = *(const uint4*)(feat + (long long)i3 * 128 + myoff);
        add8(acc, v0); add8(accB, v1); add8(acc, v2); add8(accB, v3);
    }
    for (; j + 8 <= cnt; j += 8) {
        const int4 ia = *(const int4*)(row + j);
        const int4 ib = *(const int4*)(row + j + 4);
        int i0 = sel4(ia, g), i1 = sel4(ib, g);
        uint4 v0 = *(const uint4*)(feat + (long long)i0 * 128 + myoff);
        uint4 v1 = *(const uint4*)(feat + (long long)i1 * 128 + myoff);
        add8(acc, v0); add8(accB, v1);
    }
    for (; j + 4 <= cnt; j += 4) {
        const int4 ia = *(const int4*)(row + j);
        int i0 = sel4(ia, g);
        uint4 v = *(const uint4*)(feat + (long long)i0 * 128 + myoff);
        add8(acc, v);
    }
    int rem = cnt - j;  // 0..3
    if (rem > 0) {
        int idx = row[j + (g < rem ? g : 0)];
        uint4 v = *(const uint4*)(feat + (long long)idx * 128 + myoff);
        if (g < rem) add8(acc, v);
    }
#pragma unroll
    for (int k = 0; k < 8; ++k) acc[k] += accB[k];
#pragma unroll
    for (int k = 0; k < 8; ++k) acc[k] += __shfl_xor(acc[k], 16, 64);
#pragma unroll
    for (int k = 0; k < 8; ++k) acc[k] += __shfl_xor(acc[k], 32, 64);

    if (lane < 16) {
        c0.x += acc[0]; c0.y += acc[1]; c0.z += acc[2]; c0.w += acc[3];
        c1.x += acc[4]; c1.y += acc[5]; c1.z += acc[6]; c1.w += acc[7];
        *(float4*)(orow) = c0;
        *(float4*)(orow + 4) = c1;
    }
}

// ---------------- MFMA dual-segment GEMM: BM=128, BN=64, BK=64 ----------------
// Staging via global_load_lds width-16, linear LDS rows, XOR chunk swizzle.
// MODE 0: C0 = relu(acc + bias) -> h bf16 [M][Nfull]
// MODE 1: cols<128 -> C0 = p bf16 [M][128]; cols>=128 -> C1 = out fp32 [M][128] + bias
template <int MODE>
__global__ __launch_bounds__(256)
void mfma_gemm(const unsigned short* __restrict__ A1, int K1,
               const unsigned short* __restrict__ A2, int K2,
               const unsigned short* __restrict__ BT,
               const float* __restrict__ bias,
               void* __restrict__ C0v, void* __restrict__ C1v,
               int M, int Nfull) {
    __shared__ unsigned short A_lds[128][64];
    __shared__ unsigned short B_lds[64][64];

    const int t = threadIdx.x;
    const int lane = t & 63;
    const int w = t >> 6;       // wave row-group 0..3
    const int l15 = lane & 15;
    const int quad = lane >> 4;
    const int row0 = blockIdx.x * 128;
    const int col0 = blockIdx.y * 64;
    const int Ktot = K1 + K2;

    floatx4 acc[2][4];
#pragma unroll
    for (int i = 0; i < 2; ++i)
#pragma unroll
        for (int cf = 0; cf < 4; ++cf) acc[i][cf] = (floatx4){0.f, 0.f, 0.f, 0.f};

    const int lr = lane >> 3;            // 0..7
    const int gchunk = (lane & 7) ^ lr;  // involution partner of (l&7) for row%8 == lr

    for (int k0 = 0; k0 < Ktot; k0 += 64) {
        const unsigned short* Ap;
        int astride, acol;
        if (k0 < K1) { Ap = A1; astride = K1; acol = k0; }
        else         { Ap = A2; astride = K2; acol = k0 - K1; }
#pragma unroll
        for (int it = 0; it < 4; ++it) {
            int r = w * 32 + it * 8 + lr;
            int gr = row0 + r; if (gr >= M) gr = M - 1;
            gload_lds16(Ap + (long long)gr * astride + acol + gchunk * 8,
                        &A_lds[w * 32 + it * 8][0]);
        }
#pragma unroll
        for (int it = 0; it < 2; ++it) {
            int r = w * 16 + it * 8 + lr;
            gload_lds16(BT + (long long)(col0 + r) * Ktot + k0 + gchunk * 8,
                        &B_lds[w * 16 + it * 8][0]);
        }
        __syncthreads();
#pragma unroll
        for (int kc = 0; kc < 2; ++kc) {
            const int sa = ((kc * 4 + quad) ^ (l15 & 7)) * 8;  // swizzled short offset
            short8 a0 = *(short8*)&A_lds[w * 32 + l15][sa];
            short8 a1 = *(short8*)&A_lds[w * 32 + 16 + l15][sa];
            short8 bb[4];
#pragma unroll
            for (int cf = 0; cf < 4; ++cf)
                bb[cf] = *(short8*)&B_lds[cf * 16 + l15][sa];
#pragma unroll
            for (int cf = 0; cf < 4; ++cf) {
                acc[0][cf] = __builtin_amdgcn_mfma_f32_16x16x32_bf16(a0, bb[cf], acc[0][cf], 0, 0, 0);
                acc[1][cf] = __builtin_amdgcn_mfma_f32_16x16x32_bf16(a1, bb[cf], acc[1][cf], 0, 0, 0);
            }
        }
        __syncthreads();
    }

    // epilogue: row = row0 + w*32 + i*16 + quad*4 + reg; col = col0 + cf*16 + l15
    const int rbase = row0 + w * 32 + quad * 4;

    if (MODE == 0) {
        unsigned short* C0 = (unsigned short*)C0v;
#pragma unroll
        for (int cf = 0; cf < 4; ++cf) {
            const int cj = col0 + cf * 16 + l15;
            const float bi = bias[cj];
#pragma unroll
            for (int i = 0; i < 2; ++i) {
#pragma unroll
                for (int reg = 0; reg < 4; ++reg) {
                    int r = rbase + i * 16 + reg;
                    if (r >= M) continue;
                    C0[(long long)r * Nfull + cj] = f2bf(fmaxf(acc[i][cf][reg] + bi, 0.f));
                }
            }
        }
    } else {
        if (col0 < 128) {
            unsigned short* C0 = (unsigned short*)C0v;
#pragma unroll
            for (int cf = 0; cf < 4; ++cf) {
                const int cj = col0 + cf * 16 + l15;
#pragma unroll
                for (int i = 0; i < 2; ++i) {
#pragma unroll
                    for (int reg = 0; reg < 4; ++reg) {
                        int r = rbase + i * 16 + reg;
                        if (r >= M) continue;
                        C0[(long long)r * 128 + cj] = f2bf(acc[i][cf][reg]);
                    }
                }
            }
        } else {
            float* C1 = (float*)C1v;
#pragma unroll
            for (int cf = 0; cf < 4; ++cf) {
                const int d = col0 - 128 + cf * 16 + l15;
                const float bi = bias[d];
#pragma unroll
                for (int i = 0; i < 2; ++i) {
#pragma unroll
                    for (int reg = 0; reg < 4; ++reg) {
                        int r = rbase + i * 16 + reg;
                        if (r >= M) continue;
                        C1[(long long)r * 128 + d] = acc[i][cf][reg] + bi;
                    }
                }
            }
        }
    }
}

extern "C" void kernel_launch(void* const* d_in, const int* in_sizes, int n_in,
                              void* d_out, int out_size, void* d_ws, size_t ws_size,
                              hipStream_t stream) {
    const float* x   = (const float*)d_in[0];
    const int*   ei  = (const int*)d_in[1];
    const float* W1l = (const float*)d_in[2];
    const float* b1  = (const float*)d_in[3];
    const float* W1r = (const float*)d_in[4];
    const float* W2l = (const float*)d_in[5];
    const float* b2  = (const float*)d_in[6];
    const float* W2r = (const float*)d_in[7];
    float* out = (float*)d_out;

    const int E = in_sizes[1] / 2;
    const int* src = ei;
    const int* dst = ei + E;

    // ---- workspace layout (all 16B aligned) ----
    char* w = (char*)d_ws;
    int* cursor  = (int*)w;             w += 10016 * sizeof(int);
    int* bucket  = (int*)w;             w += (long long)N_NODES * BUCKET * sizeof(int);
    unsigned short* xb    = (unsigned short*)w; w += (long long)N_NODES * F_IN * 2;
    unsigned short* agg1b = (unsigned short*)w; w += (long long)N_NODES * F_IN * 2;
    unsigned short* W1T   = (unsigned short*)w; w += 512 * 512 * 2;
    unsigned short* W2T   = (unsigned short*)w; w += 256 * 512 * 2;
    unsigned short* h     = (unsigned short*)w; w += (long long)N_NODES * HID * 2;
    unsigned short* p     = (unsigned short*)w; w += (long long)N_NODES * C_OUT * 2;

    // ---- zero cursor (stream-ordered, graph-capturable), then fused prep+fill ----
    hipMemsetAsync(cursor, 0, 10016 * sizeof(int), stream);
    const int fill_blocks = (E + 255) / 256;
    prep_fill_kernel<<<2884 + fill_blocks, 256, 0, stream>>>(
        (const float4*)x, (uint2*)xb, W1l, W1r, W2l, W2r, W1T, W2T,
        src, dst, cursor, bucket, E);

    const int agg_blocks = (N_NODES * 64 + 255) / 256;

    // ---- layer 1 ----
    gather_agg_256<<<agg_blocks, 256, 0, stream>>>(xb, cursor, bucket, agg1b, N_NODES);
    {
        dim3 grid((N_NODES + 127) / 128, HID / 64);
        mfma_gemm<0><<<grid, 256, 0, stream>>>(agg1b, F_IN, xb, F_IN, W1T, b1,
                                               (void*)h, (void*)nullptr, N_NODES, HID);
    }

    // ---- layer 2 (aggregation swapped past the linear) ----
    {
        dim3 grid((N_NODES + 127) / 128, 256 / 64);
        mfma_gemm<1><<<grid, 256, 0, stream>>>(h, HID, h, 0, W2T, b2,
                                               (void*)p, (void*)out, N_NODES, 256);
    }
    gather_acc_128<<<agg_blocks, 256, 0, stream>>>(p, cursor, bucket, out, N_NODES);
}